// Round 7
// baseline (638.978 us; speedup 1.0000x reference)
//
#include <hip/hip_runtime.h>
#include <cstdint>
#include <cstddef>

// ---------------- problem constants ----------------
constexpr int Bn = 24;
constexpr int Dd = 128;
constexpr int Nn = 2048;
constexpr int DN = Dd * Nn;        // 262144 elements per (b, slot)
constexpr int NIT = Nn / 64;       // 32 streamed tiles
constexpr float INV_KEEP = 1.0f / 0.9f;

// ---------------- vector types ----------------
typedef __attribute__((ext_vector_type(8))) short short8;     // 8 bf16 in 4 VGPRs
typedef __attribute__((ext_vector_type(16))) float floatx16;  // MFMA 32x32 acc

union U8 { uint32_t u[4]; short8 v; uint4 q; };

__device__ __forceinline__ uint32_t f2bf(float f) {
  uint32_t u = __builtin_bit_cast(uint32_t, f);
  return (u + 0x7fffu + ((u >> 16) & 1u)) >> 16;   // RNE
}
__device__ __forceinline__ float bf2f(uint32_t h) {
  return __builtin_bit_cast(float, h << 16);
}

__device__ __forceinline__ floatx16 MFMA(short8 a, short8 b, floatx16 c) {
  return __builtin_amdgcn_mfma_f32_32x32x16_bf16(a, b, c, 0, 0, 0);
}

// async global->LDS, 16B per lane. LDS dest = wave-uniform base + lane*16.
__device__ __forceinline__ void gload_lds16(const void* g, void* l) {
  __builtin_amdgcn_global_load_lds(
      (const __attribute__((address_space(1))) void*)g,
      (__attribute__((address_space(3))) void*)l, 16, 0, 0);
}

// ---------------- threefry2x32, key = jax.random.key(42) => (0, 42) ----------------
__device__ __forceinline__ uint32_t rotl32(uint32_t x, int r) {
  return (x << r) | (x >> (32 - r));
}
__device__ __forceinline__ void tf2x32(uint32_t& x0, uint32_t& x1) {
  const uint32_t k0 = 0u, k1 = 42u, k2 = 0x1BD11BDAu ^ 0u ^ 42u;
  x0 += k0; x1 += k1;
#define TFR(r) { x0 += x1; x1 = rotl32(x1, (r)); x1 ^= x0; }
  TFR(13) TFR(15) TFR(26) TFR(6)   x0 += k1; x1 += k2 + 1u;
  TFR(17) TFR(29) TFR(16) TFR(24)  x0 += k2; x1 += k0 + 2u;
  TFR(13) TFR(15) TFR(26) TFR(6)   x0 += k0; x1 += k1 + 3u;
  TFR(17) TFR(29) TFR(16) TFR(24)  x0 += k1; x1 += k2 + 4u;
  TFR(13) TFR(15) TFR(26) TFR(6)   x0 += k2; x1 += k0 + 5u;
#undef TFR
}
__device__ __forceinline__ bool keep_flag(uint32_t j) {
  uint32_t x0 = 0u, x1 = j;       // partitionable threefry (verified passing R2-R4)
  tf2x32(x0, x1);
  return ((x0 ^ x1) >> 9) < 7549747u;
}

// ---------------- P0: sc[b,n] = sum_d Wc[b,d] C[b,d,n]; sq = Wq . Q ----------------
__global__ void scq_kernel(const float* __restrict__ Cp, const float* __restrict__ Qp,
                           const float* __restrict__ Wp,
                           float* __restrict__ sc, float* __restrict__ sq) {
  const int z = blockIdx.z;
  const int b = blockIdx.y;
  const int n = blockIdx.x * 256 + threadIdx.x;
  const float* X = z ? Qp : Cp;
  const float* Wb = Wp + b * 384 + (z ? 0 : 128);
  const float* Xb = X + (size_t)b * DN + n;
  float acc = 0.f;
#pragma unroll 8
  for (int d = 0; d < Dd; ++d) acc = fmaf(Wb[d], Xb[(size_t)d * Nn], acc);
  (z ? sq : sc)[b * Nn + n] = acc;
}

// ---------------- bias adjust: v[b,:] -= max(v[b,:]) (fixed-shift softmax) -------
// Verified passing in R3/R5/R6 (absmax 0.125).
__global__ __launch_bounds__(256) void bias_adjust_kernel(float* __restrict__ sc,
                                                          float* __restrict__ sq) {
  __shared__ float red[256];
  const int tid = threadIdx.x;
  float* v = ((blockIdx.x & 1) ? sq : sc) + (size_t)(blockIdx.x >> 1) * Nn;
  float m = -__builtin_inff();
#pragma unroll
  for (int i = 0; i < 8; ++i) m = fmaxf(m, v[tid + 256 * i]);
  red[tid] = m;
  __syncthreads();
  for (int s = 128; s > 0; s >>= 1) {
    if (tid < s) red[tid] = fmaxf(red[tid], red[tid + s]);
    __syncthreads();
  }
  const float mm = red[0];
#pragma unroll
  for (int i = 0; i < 8; ++i) v[tid + 256 * i] -= mm;
}

// ---------------- cvt: C,Q fp32 [d][n] -> bf16 [d][n] into slot0 (lo=C, hi=Q) ----
__global__ __launch_bounds__(256) void cvt_kernel(const float* __restrict__ Cp,
                                                  const float* __restrict__ Qp,
                                                  float* __restrict__ outp) {
  const size_t i = ((size_t)blockIdx.x * 256 + threadIdx.x) * 8;   // over Bn*DN
  const int b = (int)(i >> 18);
  const int rem = (int)(i & (DN - 1));
  uint16_t* d0 = (uint16_t*)(outp + (size_t)b * 4 * DN);
  {
    const float4 a = *(const float4*)(Cp + i);
    const float4 c = *(const float4*)(Cp + i + 4);
    U8 t;
    t.u[0] = f2bf(a.x) | (f2bf(a.y) << 16);
    t.u[1] = f2bf(a.z) | (f2bf(a.w) << 16);
    t.u[2] = f2bf(c.x) | (f2bf(c.y) << 16);
    t.u[3] = f2bf(c.z) | (f2bf(c.w) << 16);
    *(uint4*)(d0 + rem) = t.q;
  }
  {
    const float4 a = *(const float4*)(Qp + i);
    const float4 c = *(const float4*)(Qp + i + 4);
    U8 t;
    t.u[0] = f2bf(a.x) | (f2bf(a.y) << 16);
    t.u[1] = f2bf(a.z) | (f2bf(a.w) << 16);
    t.u[2] = f2bf(c.x) | (f2bf(c.y) << 16);
    t.u[3] = f2bf(c.z) | (f2bf(c.w) << 16);
    *(uint4*)(d0 + DN + rem) = t.q;
  }
}

// ---------------- split+transpose: X[b][d][n] fp32 -> hi/lo bf16 [b][n][d] -------
// Q -> slot1 ; C -> slot3. (hi first DN ushorts, lo next DN)
__global__ __launch_bounds__(256) void split_kernel(const float* __restrict__ Cp,
                                                    const float* __restrict__ Qp,
                                                    float* __restrict__ outp) {
  __shared__ float T[64 * 129];
  const int tid = threadIdx.x;
  const int nt = blockIdx.x, src = blockIdx.y, b = blockIdx.z;
  const float* X = (src ? Qp : Cp) + (size_t)b * DN;
  float* outb = outp + (size_t)b * 4 * DN;
  uint16_t* dsth = (uint16_t*)(outb + (size_t)(src ? 1 : 3) * DN);
  uint16_t* dstl = dsth + DN;
  const int n = nt * 64 + (tid & 63);
  const int dg0 = (tid >> 6) * 32;
#pragma unroll
  for (int r = 0; r < 32; ++r)
    T[(tid & 63) * 129 + dg0 + r] = X[(size_t)(dg0 + r) * Nn + n];
  __syncthreads();
#pragma unroll
  for (int r = 0; r < 4; ++r) {
    const int item = tid + 256 * r;
    const int row = item >> 4;
    const int ch = item & 15;
    const float* tp = T + row * 129 + ch * 8;
    U8 H, L;
#pragma unroll
    for (int e = 0; e < 4; ++e) {
      const float va = tp[2 * e], vb = tp[2 * e + 1];
      const uint32_t ha = f2bf(va), hb = f2bf(vb);
      H.u[e] = ha | (hb << 16);
      L.u[e] = f2bf(va - bf2f(ha)) | (f2bf(vb - bf2f(hb)) << 16);
    }
    const size_t o = (size_t)(nt * 64 + row) * 128 + ch * 8;
    *(uint4*)(dsth + o) = H.q;
    *(uint4*)(dstl + o) = L.q;
  }
}

// ---------------- fused flash pass: single barrier, zero in-loop vm-waits -------
// DUAL=false (P2): x=m, stream y=n. S2 weights; U2 = C . S2 -> slot2-lo (bf16).
// DUAL=true  (P34): x=n, stream y=m. S1 weights; A = Q . S1 -> slot3 (fp32);
//                   Bt = U2 . S1 -> slot0-lo (d<64) / slot2-hi (d>=64) (fp32).
// Fixed softmax shift (R3/R5/R6-verified): c3 = 3*||u_x|| + per-b max(bias) presub.
// EVERY global load crosses the barrier before consumption; the only vmcnt(0)
// in the loop is inside __syncthreads where all loads have ~full-iter cover.
// R7 deltas vs R6 (latency/convoy package):
//  - bias double-buffered (bvN issued right after stage -> full-iter cover;
//    was last-issued before the barrier = naked L2 latency every iteration)
//  - S split into 2 accumulators (dependent chain 24 -> 16 deep)
//  - s_setprio(1) around S and PV MFMA clusters (T5; co-resident blocks are
//    de-phased so the CU scheduler has role diversity to arbitrate)
template<bool DUAL>
__global__ __launch_bounds__(256, 2) void pass_kernel(
    const float* __restrict__ Cp, const float* __restrict__ Qp,
    const float* __restrict__ Wp, float* __restrict__ outp,
    const float* __restrict__ scp, const float* __restrict__ sqp) {
  __shared__ uint16_t Bs[2][2][64 * 128];  // [buf][hi/lo][y][d] swizzled, 64 KiB
  __shared__ uint16_t EsS[2][64 * 64];     // weights bf16 (swizzled), dbuf, 16 KiB

  const int tid = threadIdx.x;
  const int lane = tid & 63;
  const int w = tid >> 6;
  const int xh = w >> 1, yh = w & 1;
  const int lh = lane >> 5, l31 = lane & 31;

  // XCD-bijective mapping: 768 = 8 XCD x (3 b x 32 x-tiles)
  const int bid = blockIdx.x;
  const int jj = bid >> 3;
  const int b = (bid & 7) * 3 + (jj >> 5);
  const int x0 = (jj & 31) * 64;

  const float* Cb = Cp + (size_t)b * DN;
  const float* Qb = Qp + (size_t)b * DN;
  float* outb = outp + (size_t)b * 4 * DN;
  const float* Wmb = Wp + b * 384 + 256;

  const float* Asrc = DUAL ? Cb : Qb;        // x-side source (fp32, hi/lo split here)
  const uint16_t* V1 = (const uint16_t*)outb + (DUAL ? DN : 0);        // Qbf16 / Cbf16
  const uint16_t* V2 = DUAL ? (const uint16_t*)(outb + 2 * DN) : nullptr;  // U2bf16
  const uint16_t* BTh = (const uint16_t*)(outb + (size_t)(DUAL ? 1 : 3) * DN);
  const uint16_t* BTl = BTh + DN;
  const float* byp = (DUAL ? sqp : scp) + b * Nn;

  // ---- async staging of one 64-row hi/lo tile into Bs[bn] (pre-swizzled src) ----
  auto stage = [&](int bn, int y0n) {
#pragma unroll
    for (int j = 0; j < 4; ++j) {
      const int s = w * 256 + j * 64 + lane;
      const int y = s >> 4;
      const int cs = ((s & 15) ^ (y & 15)) * 8;
      const size_t gof = (size_t)(y0n + y) * 128 + cs;
      const int lof = (w * 256 + j * 64) * 8;   // wave-uniform
      gload_lds16(BTh + gof, &Bs[bn][0][lof]);
      gload_lds16(BTl + gof, &Bs[bn][1][lof]);
    }
  };

  // ---- x-side fragments (wm * Asrc), hi/lo split + exact sigma for shift ----
  short8 xfh[8], xfl[8];
  float sig2 = 0.f;
  {
    const int xg = x0 + xh * 32 + l31;
#pragma unroll
    for (int ks = 0; ks < 8; ++ks) {
      U8 th, tl;
#pragma unroll
      for (int e = 0; e < 4; ++e) {
        const int d0 = ks * 16 + lh * 8 + e * 2;
        const float va = Asrc[(size_t)d0 * Nn + xg] * Wmb[d0];
        const float vb = Asrc[(size_t)(d0 + 1) * Nn + xg] * Wmb[d0 + 1];
        sig2 += va * va + vb * vb;
        const uint32_t ha = f2bf(va), hb = f2bf(vb);
        th.u[e] = ha | (hb << 16);
        tl.u[e] = f2bf(va - bf2f(ha)) | (f2bf(vb - bf2f(hb)) << 16);
      }
      xfh[ks] = th.v; xfl[ks] = tl.v;
    }
  }
  sig2 += __shfl_xor(sig2, 32);           // combine the two d-halves (same x)
  const float c3 = 3.0f * sqrtf(sig2);    // fixed per-x shift [R3/R5/R6-verified]

  float s_run = 0.f;

  floatx16 aA0, aA1, aB0, aB1;
#pragma unroll
  for (int r = 0; r < 16; ++r) { aA0[r] = 0.f; aA1[r] = 0.f; }
  if constexpr (DUAL) {
#pragma unroll
    for (int r = 0; r < 16; ++r) { aB0[r] = 0.f; aB1[r] = 0.f; }
  }

  const int yrow = yh * 32 + l31;
  const int xl = xh * 32 + l31;
  const int dloc = w * 32 + l31;
  const int ybias = yh * 32 + 4 * lh;

  // ---- loop-carried V fragments + double-buffered bias ----
  short8 vf1[4], vf2[4];
  float4 bvC[4], bvN[4];

  // PV consuming the loop-carried V regs against EsS[pb] (register + LDS only)
  auto consume_pv = [&](int pb) {
    __builtin_amdgcn_s_setprio(1);
#pragma unroll
    for (int ks = 0; ks < 4; ++ks) {
      const int sw = ((2 * ks + lh) ^ (l31 & 7)) * 8;
      const short8 e0 = *(const short8*)(&EsS[pb][l31 * 64 + sw]);
      const short8 e1 = *(const short8*)(&EsS[pb][(32 + l31) * 64 + sw]);
      aA0 = MFMA(vf1[ks], e0, aA0);
      aA1 = MFMA(vf1[ks], e1, aA1);
      if constexpr (DUAL) {
        aB0 = MFMA(vf2[ks], e0, aB0);
        aB1 = MFMA(vf2[ks], e1, aB1);
      }
    }
    __builtin_amdgcn_s_setprio(0);
  };
  auto issue_v = [&](int y0p) {
    const uint16_t* v1p = V1 + (size_t)dloc * Nn + y0p + lh * 8;
#pragma unroll
    for (int ks = 0; ks < 4; ++ks)
      vf1[ks] = *(const short8*)(v1p + ks * 16);
    if constexpr (DUAL) {
      const uint16_t* v2p = V2 + (size_t)dloc * Nn + y0p + lh * 8;
#pragma unroll
      for (int ks = 0; ks < 4; ++ks)
        vf2[ks] = *(const short8*)(v2p + ks * 16);
    }
  };

  // prologue: stage tile 0; bias(0) into bvN (copied to bvC at loop top)
  stage(0, 0);
#pragma unroll
  for (int gq = 0; gq < 4; ++gq)
    bvN[gq] = *(const float4*)(byp + ybias + 8 * gq);

#pragma unroll 1
  for (int it = 0; it < NIT; ++it) {
    const int y0i = it * 64;
    const int cur = it & 1;

    // THE barrier: Bs[cur] staged, V(t-1)/bias(t) landed, Es(t-1) visible,
    // WAR windows closed. Only vmcnt(0) in the loop lives inside here.
    __syncthreads();

    // async staging for next tile (in flight through this whole iteration)
    if (it + 1 < NIT) stage(cur ^ 1, y0i + 64);

    // bias rotate + EARLY issue of bias(t+1): full-iter cover (was the naked
    // last-issued load at the barrier in R6)
#pragma unroll
    for (int gq = 0; gq < 4; ++gq) bvC[gq] = bvN[gq];
    if (it + 1 < NIT) {
#pragma unroll
      for (int gq = 0; gq < 4; ++gq)
        bvN[gq] = *(const float4*)(byp + y0i + 64 + ybias + 8 * gq);
    }

    // ---- S^T via split-bf16 MFMA: 2 accumulator chains (8-deep + 16-deep) ----
    const uint16_t* brH = &Bs[cur][0][yrow * 128];
    const uint16_t* brL = &Bs[cur][1][yrow * 128];
    floatx16 Sa, Sb;
#pragma unroll
    for (int r = 0; r < 16; ++r) { Sa[r] = 0.f; Sb[r] = 0.f; }
    __builtin_amdgcn_s_setprio(1);
#pragma unroll
    for (int ks = 0; ks < 8; ++ks) {
      const int ch = ((2 * ks + lh) ^ (yrow & 15)) * 8;
      const short8 bh = *(const short8*)(brH + ch);
      const short8 bl = *(const short8*)(brL + ch);
      Sa = MFMA(bh, xfh[ks], Sa);
      Sb = MFMA(bl, xfh[ks], Sb);
      Sb = MFMA(bh, xfl[ks], Sb);
    }
    __builtin_amdgcn_s_setprio(0);

    // ---- PV of previous tile: loop-carried V regs + Es LDS (no vm waits) ----
    if (it > 0) consume_pv(cur ^ 1);

    // ---- reissue V for THIS tile (consumed next iter, after the barrier) ----
    issue_v(y0i);

    // ---- exp (fixed shift) + Es(t) write + lane-local sum ----
#pragma unroll
    for (int gq = 0; gq < 4; ++gq) {
      const float e0 = __expf(Sa[4 * gq + 0] + Sb[4 * gq + 0] + (bvC[gq].x - c3));
      const float e1 = __expf(Sa[4 * gq + 1] + Sb[4 * gq + 1] + (bvC[gq].y - c3));
      const float e2 = __expf(Sa[4 * gq + 2] + Sb[4 * gq + 2] + (bvC[gq].z - c3));
      const float e3 = __expf(Sa[4 * gq + 3] + Sb[4 * gq + 3] + (bvC[gq].w - c3));
      s_run += (e0 + e1) + (e2 + e3);
      uint2 pk;
      pk.x = f2bf(e0) | (f2bf(e1) << 16);
      pk.y = f2bf(e2) | (f2bf(e3) << 16);
      const int c = 4 * yh + gq;
      *(uint2*)(&EsS[cur][xl * 64 + ((c ^ (xl & 7)) * 8 + 4 * lh)]) = pk;
    }
  }

  // ---- drain: PV of the last tile (V already in regs) ----
  __syncthreads();
  consume_pv((NIT - 1) & 1);

  // ---- combine sum partials (lh via shuffle, yh via LDS aliased into Es[0]) ----
  s_run += __shfl_xor(s_run, 32);
  float* spart = (float*)(&EsS[0][0]);    // Es[0] dead after last PV (reads Es[1])
  if (lh == 0) spart[yh * 64 + xl] = s_run;
  __syncthreads();
  const float inv0 = 1.0f / (spart[l31] + spart[64 + l31]);
  const float inv1 = 1.0f / (spart[32 + l31] + spart[96 + l31]);
#pragma unroll
  for (int r = 0; r < 16; ++r) {
    const int d = w * 32 + (r & 3) + 8 * (r >> 2) + 4 * lh;
    if constexpr (DUAL) {
      // A -> slot3 fp32
      float* oa = outb + 3 * DN + (size_t)d * Nn + x0;
      oa[l31] = aA0[r] * inv0;
      oa[32 + l31] = aA1[r] * inv1;
      // Bt -> slot0-lo (d<64) / slot2-hi (d>=64) fp32 (wave-uniform branch)
      float* ob = (d < 64) ? (outb + (size_t)d * Nn + x0)
                           : (outb + 2 * DN + DN / 2 + (size_t)(d - 64) * Nn + x0);
      ob[l31] = aB0[r] * inv0;
      ob[32 + l31] = aB1[r] * inv1;
    } else {
      // U2 -> slot2-lo bf16 [d][n]
      uint16_t* ou = (uint16_t*)(outb + 2 * DN) + (size_t)d * Nn + x0;
      ou[l31] = (uint16_t)f2bf(aA0[r] * inv0);
      ou[32 + l31] = (uint16_t)f2bf(aA1[r] * inv1);
    }
  }
}

// ---------------- epilogue: concat + exact-JAX dropout, in place ----------------
// At entry: slot3=A fp32, Bt fp32 @ slot0-lo (d<64) / slot2-hi (d>=64).
// Final: slot0=drop(C), slot1=drop(A), slot2=drop(C*A), slot3=drop(C*Bt).
// Thread owns all 4 slot positions + its A/Bt reads share its flat index: race-free.
__global__ void epilogue_kernel(const float* __restrict__ Cp, float* __restrict__ outp) {
  const int g = blockIdx.x * 256 + threadIdx.x;
  const int b = g >> 18;
  const int rem = g & ((1 << 18) - 1);
  const int dd = rem >> 11;
  const float c = Cp[g];
  const int base = (b << 20) + rem;
  const float a = outp[base + (3 << 18)];                       // A from slot3
  const float bt = outp[base + ((dd >= 64) ? (2 << 18) : 0)];   // Bt split regions
  const float vals[4] = {c, a, c * a, c * bt};
#pragma unroll
  for (int s = 0; s < 4; ++s) {
    const int j = base + (s << 18);
    outp[j] = keep_flag((uint32_t)j) ? vals[s] * INV_KEEP : 0.0f;
  }
}

// ---------------- launch ----------------
extern "C" void kernel_launch(void* const* d_in, const int* in_sizes, int n_in,
                              void* d_out, int out_size, void* d_ws, size_t ws_size,
                              hipStream_t stream) {
  (void)in_sizes; (void)n_in; (void)out_size; (void)ws_size;
  const float* C = (const float*)d_in[0];
  const float* Q = (const float*)d_in[1];
  const float* W = (const float*)d_in[2];
  float* out = (float*)d_out;
  float* ws = (float*)d_ws;

  float* sc = ws;             // [B*N]
  float* sq = ws + Bn * Nn;   // [B*M]

  cvt_kernel<<<(Bn * DN) / (256 * 8), 256, 0, stream>>>(C, Q, out);
  split_kernel<<<dim3(Nn / 64, 2, Bn), 256, 0, stream>>>(C, Q, out);
  scq_kernel<<<dim3(Nn / 256, Bn, 2), 256, 0, stream>>>(C, Q, W, sc, sq);
  bias_adjust_kernel<<<2 * Bn, 256, 0, stream>>>(sc, sq);
  pass_kernel<false><<<dim3(Nn / 64 * Bn), 256, 0, stream>>>(C, Q, W, out, sc, sq);
  pass_kernel<true><<<dim3(Nn / 64 * Bn), 256, 0, stream>>>(C, Q, W, out, sc, sq);
  epilogue_kernel<<<(Bn * DN) / 256, 256, 0, stream>>>(C, out);
}

// Round 8
// 542.072 us; speedup vs baseline: 1.1788x; 1.1788x over previous
//
#include <hip/hip_runtime.h>
#include <cstdint>
#include <cstddef>

// ---------------- problem constants ----------------
constexpr int Bn = 24;
constexpr int Dd = 128;
constexpr int Nn = 2048;
constexpr int DN = Dd * Nn;        // 262144 elements per (b, slot)
constexpr int NIT = Nn / 64;       // 32 streamed tiles
constexpr float INV_KEEP = 1.0f / 0.9f;

// ---------------- vector types ----------------
typedef __attribute__((ext_vector_type(8))) short short8;     // 8 bf16 in 4 VGPRs
typedef __attribute__((ext_vector_type(16))) float floatx16;  // MFMA 32x32 acc

union U8 { uint32_t u[4]; short8 v; uint4 q; };

__device__ __forceinline__ uint32_t f2bf(float f) {
  uint32_t u = __builtin_bit_cast(uint32_t, f);
  return (u + 0x7fffu + ((u >> 16) & 1u)) >> 16;   // RNE
}
__device__ __forceinline__ float bf2f(uint32_t h) {
  return __builtin_bit_cast(float, h << 16);
}

__device__ __forceinline__ floatx16 MFMA(short8 a, short8 b, floatx16 c) {
  return __builtin_amdgcn_mfma_f32_32x32x16_bf16(a, b, c, 0, 0, 0);
}

// async global->LDS, 16B per lane. LDS dest = wave-uniform base + lane*16.
__device__ __forceinline__ void gload_lds16(const void* g, void* l) {
  __builtin_amdgcn_global_load_lds(
      (const __attribute__((address_space(1))) void*)g,
      (__attribute__((address_space(3))) void*)l, 16, 0, 0);
}

// ---------------- threefry2x32, key = jax.random.key(42) => (0, 42) ----------------
__device__ __forceinline__ uint32_t rotl32(uint32_t x, int r) {
  return (x << r) | (x >> (32 - r));
}
__device__ __forceinline__ void tf2x32(uint32_t& x0, uint32_t& x1) {
  const uint32_t k0 = 0u, k1 = 42u, k2 = 0x1BD11BDAu ^ 0u ^ 42u;
  x0 += k0; x1 += k1;
#define TFR(r) { x0 += x1; x1 = rotl32(x1, (r)); x1 ^= x0; }
  TFR(13) TFR(15) TFR(26) TFR(6)   x0 += k1; x1 += k2 + 1u;
  TFR(17) TFR(29) TFR(16) TFR(24)  x0 += k2; x1 += k0 + 2u;
  TFR(13) TFR(15) TFR(26) TFR(6)   x0 += k0; x1 += k1 + 3u;
  TFR(17) TFR(29) TFR(16) TFR(24)  x0 += k1; x1 += k2 + 4u;
  TFR(13) TFR(15) TFR(26) TFR(6)   x0 += k2; x1 += k0 + 5u;
#undef TFR
}
__device__ __forceinline__ bool keep_flag(uint32_t j) {
  uint32_t x0 = 0u, x1 = j;       // partitionable threefry (verified passing R2-R4)
  tf2x32(x0, x1);
  return ((x0 ^ x1) >> 9) < 7549747u;
}

// ---------------- P0: sc[b,n] = sum_d Wc[b,d] C[b,d,n]; sq = Wq . Q ----------------
__global__ void scq_kernel(const float* __restrict__ Cp, const float* __restrict__ Qp,
                           const float* __restrict__ Wp,
                           float* __restrict__ sc, float* __restrict__ sq) {
  const int z = blockIdx.z;
  const int b = blockIdx.y;
  const int n = blockIdx.x * 256 + threadIdx.x;
  const float* X = z ? Qp : Cp;
  const float* Wb = Wp + b * 384 + (z ? 0 : 128);
  const float* Xb = X + (size_t)b * DN + n;
  float acc = 0.f;
#pragma unroll 8
  for (int d = 0; d < Dd; ++d) acc = fmaf(Wb[d], Xb[(size_t)d * Nn], acc);
  (z ? sq : sc)[b * Nn + n] = acc;
}

// ---------------- bias adjust: v[b,:] -= max(v[b,:]) (fixed-shift softmax) -------
// Verified passing in R3/R5/R6 (absmax 0.125).
__global__ __launch_bounds__(256) void bias_adjust_kernel(float* __restrict__ sc,
                                                          float* __restrict__ sq) {
  __shared__ float red[256];
  const int tid = threadIdx.x;
  float* v = ((blockIdx.x & 1) ? sq : sc) + (size_t)(blockIdx.x >> 1) * Nn;
  float m = -__builtin_inff();
#pragma unroll
  for (int i = 0; i < 8; ++i) m = fmaxf(m, v[tid + 256 * i]);
  red[tid] = m;
  __syncthreads();
  for (int s = 128; s > 0; s >>= 1) {
    if (tid < s) red[tid] = fmaxf(red[tid], red[tid + s]);
    __syncthreads();
  }
  const float mm = red[0];
#pragma unroll
  for (int i = 0; i < 8; ++i) v[tid + 256 * i] -= mm;
}

// ---------------- cvt: C,Q fp32 [d][n] -> bf16 [d][n] into slot0 (lo=C, hi=Q) ----
__global__ __launch_bounds__(256) void cvt_kernel(const float* __restrict__ Cp,
                                                  const float* __restrict__ Qp,
                                                  float* __restrict__ outp) {
  const size_t i = ((size_t)blockIdx.x * 256 + threadIdx.x) * 8;   // over Bn*DN
  const int b = (int)(i >> 18);
  const int rem = (int)(i & (DN - 1));
  uint16_t* d0 = (uint16_t*)(outp + (size_t)b * 4 * DN);
  {
    const float4 a = *(const float4*)(Cp + i);
    const float4 c = *(const float4*)(Cp + i + 4);
    U8 t;
    t.u[0] = f2bf(a.x) | (f2bf(a.y) << 16);
    t.u[1] = f2bf(a.z) | (f2bf(a.w) << 16);
    t.u[2] = f2bf(c.x) | (f2bf(c.y) << 16);
    t.u[3] = f2bf(c.z) | (f2bf(c.w) << 16);
    *(uint4*)(d0 + rem) = t.q;
  }
  {
    const float4 a = *(const float4*)(Qp + i);
    const float4 c = *(const float4*)(Qp + i + 4);
    U8 t;
    t.u[0] = f2bf(a.x) | (f2bf(a.y) << 16);
    t.u[1] = f2bf(a.z) | (f2bf(a.w) << 16);
    t.u[2] = f2bf(c.x) | (f2bf(c.y) << 16);
    t.u[3] = f2bf(c.z) | (f2bf(c.w) << 16);
    *(uint4*)(d0 + DN + rem) = t.q;
  }
}

// ---------------- split+transpose: X[b][d][n] fp32 -> hi/lo bf16 [b][n][d] -------
// Q -> slot1 ; C -> slot3. (hi first DN ushorts, lo next DN)
__global__ __launch_bounds__(256) void split_kernel(const float* __restrict__ Cp,
                                                    const float* __restrict__ Qp,
                                                    float* __restrict__ outp) {
  __shared__ float T[64 * 129];
  const int tid = threadIdx.x;
  const int nt = blockIdx.x, src = blockIdx.y, b = blockIdx.z;
  const float* X = (src ? Qp : Cp) + (size_t)b * DN;
  float* outb = outp + (size_t)b * 4 * DN;
  uint16_t* dsth = (uint16_t*)(outb + (size_t)(src ? 1 : 3) * DN);
  uint16_t* dstl = dsth + DN;
  const int n = nt * 64 + (tid & 63);
  const int dg0 = (tid >> 6) * 32;
#pragma unroll
  for (int r = 0; r < 32; ++r)
    T[(tid & 63) * 129 + dg0 + r] = X[(size_t)(dg0 + r) * Nn + n];
  __syncthreads();
#pragma unroll
  for (int r = 0; r < 4; ++r) {
    const int item = tid + 256 * r;
    const int row = item >> 4;
    const int ch = item & 15;
    const float* tp = T + row * 129 + ch * 8;
    U8 H, L;
#pragma unroll
    for (int e = 0; e < 4; ++e) {
      const float va = tp[2 * e], vb = tp[2 * e + 1];
      const uint32_t ha = f2bf(va), hb = f2bf(vb);
      H.u[e] = ha | (hb << 16);
      L.u[e] = f2bf(va - bf2f(ha)) | (f2bf(vb - bf2f(hb)) << 16);
    }
    const size_t o = (size_t)(nt * 64 + row) * 128 + ch * 8;
    *(uint4*)(dsth + o) = H.q;
    *(uint4*)(dstl + o) = L.q;
  }
}

// ---------------- fused flash pass: single barrier, zero in-loop vm-waits -------
// DUAL=false (P2): x=m, stream y=n. S2 weights; U2 = C . S2 -> slot2-lo (bf16).
// DUAL=true  (P34): x=n, stream y=m. S1 weights; A = Q . S1 -> slot3 (fp32);
//                   Bt = U2 . S1 -> slot0-lo (d<64) / slot2-hi (d>=64) (fp32).
// Fixed softmax shift (R3/R5/R6-verified): c3 = 3*||u_x|| + per-b max(bias) presub.
// EVERY global load crosses the barrier before consumption; the only vmcnt(0)
// in the loop is inside __syncthreads where all loads have ~full-iter cover.
// R8 deltas vs R6:
//  - amdgpu_waves_per_eu(2,2): allocator optimizes for exactly 2 waves/EU
//    (occupancy is LDS-capped at 2 blocks/CU anyway) -> VGPR budget 256,
//    breaking the observed 128-VGPR heuristic ceiling that caused R0-R3/R7
//    scratch spills.
//  - bias double-buffered, issued right after stage -> full-iter cover (R6
//    issued it last-before-barrier: naked L1/L2 latency at every in-order
//    vmcnt(0) drain inside __syncthreads).
template<bool DUAL>
__global__ __attribute__((amdgpu_waves_per_eu(2, 2)))
__launch_bounds__(256) void pass_kernel(
    const float* __restrict__ Cp, const float* __restrict__ Qp,
    const float* __restrict__ Wp, float* __restrict__ outp,
    const float* __restrict__ scp, const float* __restrict__ sqp) {
  __shared__ uint16_t Bs[2][2][64 * 128];  // [buf][hi/lo][y][d] swizzled, 64 KiB
  __shared__ uint16_t EsS[2][64 * 64];     // weights bf16 (swizzled), dbuf, 16 KiB

  const int tid = threadIdx.x;
  const int lane = tid & 63;
  const int w = tid >> 6;
  const int xh = w >> 1, yh = w & 1;
  const int lh = lane >> 5, l31 = lane & 31;

  // XCD-bijective mapping: 768 = 8 XCD x (3 b x 32 x-tiles)
  const int bid = blockIdx.x;
  const int jj = bid >> 3;
  const int b = (bid & 7) * 3 + (jj >> 5);
  const int x0 = (jj & 31) * 64;

  const float* Cb = Cp + (size_t)b * DN;
  const float* Qb = Qp + (size_t)b * DN;
  float* outb = outp + (size_t)b * 4 * DN;
  const float* Wmb = Wp + b * 384 + 256;

  const float* Asrc = DUAL ? Cb : Qb;        // x-side source (fp32, hi/lo split here)
  const uint16_t* V1 = (const uint16_t*)outb + (DUAL ? DN : 0);        // Qbf16 / Cbf16
  const uint16_t* V2 = DUAL ? (const uint16_t*)(outb + 2 * DN) : nullptr;  // U2bf16
  const uint16_t* BTh = (const uint16_t*)(outb + (size_t)(DUAL ? 1 : 3) * DN);
  const uint16_t* BTl = BTh + DN;
  const float* byp = (DUAL ? sqp : scp) + b * Nn;

  // ---- async staging of one 64-row hi/lo tile into Bs[bn] (pre-swizzled src) ----
  auto stage = [&](int bn, int y0n) {
#pragma unroll
    for (int j = 0; j < 4; ++j) {
      const int s = w * 256 + j * 64 + lane;
      const int y = s >> 4;
      const int cs = ((s & 15) ^ (y & 15)) * 8;
      const size_t gof = (size_t)(y0n + y) * 128 + cs;
      const int lof = (w * 256 + j * 64) * 8;   // wave-uniform
      gload_lds16(BTh + gof, &Bs[bn][0][lof]);
      gload_lds16(BTl + gof, &Bs[bn][1][lof]);
    }
  };

  // ---- x-side fragments (wm * Asrc), hi/lo split + exact sigma for shift ----
  short8 xfh[8], xfl[8];
  float sig2 = 0.f;
  {
    const int xg = x0 + xh * 32 + l31;
#pragma unroll
    for (int ks = 0; ks < 8; ++ks) {
      U8 th, tl;
#pragma unroll
      for (int e = 0; e < 4; ++e) {
        const int d0 = ks * 16 + lh * 8 + e * 2;
        const float va = Asrc[(size_t)d0 * Nn + xg] * Wmb[d0];
        const float vb = Asrc[(size_t)(d0 + 1) * Nn + xg] * Wmb[d0 + 1];
        sig2 += va * va + vb * vb;
        const uint32_t ha = f2bf(va), hb = f2bf(vb);
        th.u[e] = ha | (hb << 16);
        tl.u[e] = f2bf(va - bf2f(ha)) | (f2bf(vb - bf2f(hb)) << 16);
      }
      xfh[ks] = th.v; xfl[ks] = tl.v;
    }
  }
  sig2 += __shfl_xor(sig2, 32);           // combine the two d-halves (same x)
  const float c3 = 3.0f * sqrtf(sig2);    // fixed per-x shift [R3/R5/R6-verified]

  float s_run = 0.f;

  floatx16 aA0, aA1, aB0, aB1;
#pragma unroll
  for (int r = 0; r < 16; ++r) { aA0[r] = 0.f; aA1[r] = 0.f; }
  if constexpr (DUAL) {
#pragma unroll
    for (int r = 0; r < 16; ++r) { aB0[r] = 0.f; aB1[r] = 0.f; }
  }

  const int yrow = yh * 32 + l31;
  const int xl = xh * 32 + l31;
  const int dloc = w * 32 + l31;
  const int ybias = yh * 32 + 4 * lh;

  // ---- loop-carried V fragments + double-buffered bias ----
  short8 vf1[4], vf2[4];
  float4 bvC[4], bvN[4];

  // PV consuming the loop-carried V regs against EsS[pb] (register + LDS only)
  auto consume_pv = [&](int pb) {
#pragma unroll
    for (int ks = 0; ks < 4; ++ks) {
      const int sw = ((2 * ks + lh) ^ (l31 & 7)) * 8;
      const short8 e0 = *(const short8*)(&EsS[pb][l31 * 64 + sw]);
      const short8 e1 = *(const short8*)(&EsS[pb][(32 + l31) * 64 + sw]);
      aA0 = MFMA(vf1[ks], e0, aA0);
      aA1 = MFMA(vf1[ks], e1, aA1);
      if constexpr (DUAL) {
        aB0 = MFMA(vf2[ks], e0, aB0);
        aB1 = MFMA(vf2[ks], e1, aB1);
      }
    }
  };
  auto issue_v = [&](int y0p) {
    const uint16_t* v1p = V1 + (size_t)dloc * Nn + y0p + lh * 8;
#pragma unroll
    for (int ks = 0; ks < 4; ++ks)
      vf1[ks] = *(const short8*)(v1p + ks * 16);
    if constexpr (DUAL) {
      const uint16_t* v2p = V2 + (size_t)dloc * Nn + y0p + lh * 8;
#pragma unroll
      for (int ks = 0; ks < 4; ++ks)
        vf2[ks] = *(const short8*)(v2p + ks * 16);
    }
  };

  // prologue: stage tile 0; bias(0) into bvN (rotated into bvC at loop top)
  stage(0, 0);
#pragma unroll
  for (int gq = 0; gq < 4; ++gq)
    bvN[gq] = *(const float4*)(byp + ybias + 8 * gq);

#pragma unroll 1
  for (int it = 0; it < NIT; ++it) {
    const int y0i = it * 64;
    const int cur = it & 1;

    // THE barrier: Bs[cur] staged, V(t-1)/bias(t) landed, Es(t-1) visible,
    // WAR windows closed. Only vmcnt(0) in the loop lives inside here.
    __syncthreads();

    // async staging for next tile (in flight through this whole iteration)
    if (it + 1 < NIT) stage(cur ^ 1, y0i + 64);

    // bias rotate + EARLY issue of bias(t+1): full-iter cover (was the naked
    // last-issued load at the barrier in R6)
#pragma unroll
    for (int gq = 0; gq < 4; ++gq) bvC[gq] = bvN[gq];
    if (it + 1 < NIT) {
#pragma unroll
      for (int gq = 0; gq < 4; ++gq)
        bvN[gq] = *(const float4*)(byp + y0i + 64 + ybias + 8 * gq);
    }

    // ---- S^T: single 24-deep same-acc MFMA chain (full-rate) ----
    const uint16_t* brH = &Bs[cur][0][yrow * 128];
    const uint16_t* brL = &Bs[cur][1][yrow * 128];
    floatx16 S;
#pragma unroll
    for (int r = 0; r < 16; ++r) S[r] = 0.f;
#pragma unroll
    for (int ks = 0; ks < 8; ++ks) {
      const int ch = ((2 * ks + lh) ^ (yrow & 15)) * 8;
      const short8 bh = *(const short8*)(brH + ch);
      const short8 bl = *(const short8*)(brL + ch);
      S = MFMA(bh, xfh[ks], S);
      S = MFMA(bl, xfh[ks], S);
      S = MFMA(bh, xfl[ks], S);
    }

    // ---- PV of previous tile: loop-carried V regs + Es LDS (no vm waits) ----
    if (it > 0) consume_pv(cur ^ 1);

    // ---- reissue V for THIS tile (consumed next iter, after the barrier) ----
    issue_v(y0i);

    // ---- exp (fixed shift) + Es(t) write + lane-local sum ----
#pragma unroll
    for (int gq = 0; gq < 4; ++gq) {
      const float e0 = __expf(S[4 * gq + 0] + (bvC[gq].x - c3));
      const float e1 = __expf(S[4 * gq + 1] + (bvC[gq].y - c3));
      const float e2 = __expf(S[4 * gq + 2] + (bvC[gq].z - c3));
      const float e3 = __expf(S[4 * gq + 3] + (bvC[gq].w - c3));
      s_run += (e0 + e1) + (e2 + e3);
      uint2 pk;
      pk.x = f2bf(e0) | (f2bf(e1) << 16);
      pk.y = f2bf(e2) | (f2bf(e3) << 16);
      const int c = 4 * yh + gq;
      *(uint2*)(&EsS[cur][xl * 64 + ((c ^ (xl & 7)) * 8 + 4 * lh)]) = pk;
    }
  }

  // ---- drain: PV of the last tile (V already in regs) ----
  __syncthreads();
  consume_pv((NIT - 1) & 1);

  // ---- combine sum partials (lh via shuffle, yh via LDS aliased into Es[0]) ----
  s_run += __shfl_xor(s_run, 32);
  float* spart = (float*)(&EsS[0][0]);    // Es[0] dead after last PV (reads Es[1])
  if (lh == 0) spart[yh * 64 + xl] = s_run;
  __syncthreads();
  const float inv0 = 1.0f / (spart[l31] + spart[64 + l31]);
  const float inv1 = 1.0f / (spart[32 + l31] + spart[96 + l31]);
#pragma unroll
  for (int r = 0; r < 16; ++r) {
    const int d = w * 32 + (r & 3) + 8 * (r >> 2) + 4 * lh;
    if constexpr (DUAL) {
      // A -> slot3 fp32
      float* oa = outb + 3 * DN + (size_t)d * Nn + x0;
      oa[l31] = aA0[r] * inv0;
      oa[32 + l31] = aA1[r] * inv1;
      // Bt -> slot0-lo (d<64) / slot2-hi (d>=64) fp32 (wave-uniform branch)
      float* ob = (d < 64) ? (outb + (size_t)d * Nn + x0)
                           : (outb + 2 * DN + DN / 2 + (size_t)(d - 64) * Nn + x0);
      ob[l31] = aB0[r] * inv0;
      ob[32 + l31] = aB1[r] * inv1;
    } else {
      // U2 -> slot2-lo bf16 [d][n]
      uint16_t* ou = (uint16_t*)(outb + 2 * DN) + (size_t)d * Nn + x0;
      ou[l31] = (uint16_t)f2bf(aA0[r] * inv0);
      ou[32 + l31] = (uint16_t)f2bf(aA1[r] * inv1);
    }
  }
}

// ---------------- epilogue: concat + exact-JAX dropout, in place ----------------
// At entry: slot3=A fp32, Bt fp32 @ slot0-lo (d<64) / slot2-hi (d>=64).
// Final: slot0=drop(C), slot1=drop(A), slot2=drop(C*A), slot3=drop(C*Bt).
// Thread owns all 4 slot positions + its A/Bt reads share its flat index: race-free.
__global__ void epilogue_kernel(const float* __restrict__ Cp, float* __restrict__ outp) {
  const int g = blockIdx.x * 256 + threadIdx.x;
  const int b = g >> 18;
  const int rem = g & ((1 << 18) - 1);
  const int dd = rem >> 11;
  const float c = Cp[g];
  const int base = (b << 20) + rem;
  const float a = outp[base + (3 << 18)];                       // A from slot3
  const float bt = outp[base + ((dd >= 64) ? (2 << 18) : 0)];   // Bt split regions
  const float vals[4] = {c, a, c * a, c * bt};
#pragma unroll
  for (int s = 0; s < 4; ++s) {
    const int j = base + (s << 18);
    outp[j] = keep_flag((uint32_t)j) ? vals[s] * INV_KEEP : 0.0f;
  }
}

// ---------------- launch ----------------
extern "C" void kernel_launch(void* const* d_in, const int* in_sizes, int n_in,
                              void* d_out, int out_size, void* d_ws, size_t ws_size,
                              hipStream_t stream) {
  (void)in_sizes; (void)n_in; (void)out_size; (void)ws_size;
  const float* C = (const float*)d_in[0];
  const float* Q = (const float*)d_in[1];
  const float* W = (const float*)d_in[2];
  float* out = (float*)d_out;
  float* ws = (float*)d_ws;

  float* sc = ws;             // [B*N]
  float* sq = ws + Bn * Nn;   // [B*M]

  cvt_kernel<<<(Bn * DN) / (256 * 8), 256, 0, stream>>>(C, Q, out);
  split_kernel<<<dim3(Nn / 64, 2, Bn), 256, 0, stream>>>(C, Q, out);
  scq_kernel<<<dim3(Nn / 256, Bn, 2), 256, 0, stream>>>(C, Q, W, sc, sq);
  bias_adjust_kernel<<<2 * Bn, 256, 0, stream>>>(sc, sq);
  pass_kernel<false><<<dim3(Nn / 64 * Bn), 256, 0, stream>>>(C, Q, W, out, sc, sq);
  pass_kernel<true><<<dim3(Nn / 64 * Bn), 256, 0, stream>>>(C, Q, W, out, sc, sq);
  epilogue_kernel<<<(Bn * DN) / 256, 256, 0, stream>>>(C, out);
}